// Round 13
// baseline (259.873 us; speedup 1.0000x reference)
//
#include <hip/hip_runtime.h>

// 1D Euler, Roe flux + Harten entropy fix, 32 steps. Round 13:
// carry sqrt(rho) and (E+p)/sqrt(rho) across steps; 5-float exchanges.
//
// Round-12 ledger (proven): kernel 157 us = 95 us VALU issue + ~62 us
// {dt IC hop ~1.2us x 32, IO, ramp}; bench = kernel + ~81 us harness.
// The dt protocol is one store->load hop (latency-optimal); attack VALU:
//  - Update already computes q2 = frsq(r2). Deriving cs = r2*q2 (bit-
//    identical to next step's recompute) and cg = (E2+p2)*q2 (uses the
//    CONSERVATIVE E2, like the reference) kills the per-step 6-cell
//    precompute (6 frsq + ~40 flops/thread).
//  - Neighbor exchange widens to 5 floats (r,u,p,s,g) via LDS / IC halo:
//    neighbors never recomputed; block-boundary fluxes bit-consistent.
//  - frcp for the two per-step divides (identical bits on all blocks).
//  - Coalesced bmax poll loads (brow[lane + 64*j]).
// Everything else byte-level identical to round 12's proven skeleton:
// one-hop sign-bit dt publish, LDS flux exchange, per-step halo rows,
// unconditional cooperative launch (NO host queries — capture lesson).

#define NXC   1048576
#define GAM   1.4f
#define GM1   0.4f
#define IGM1  2.5f
#define CFLC  0.5f
#define DXC   1e-3f
#define IDXC  1000.0f
#define EFIX  0.1f
#define NSTEPS 32
#define NSLOT  (NSTEPS + 1)

#define ABLK  1024
#define ACPT  4
#define ATILE (ABLK*ACPT)      // 4096
#define ANBLK (NXC/ATILE)      // 256 blocks = 1/CU (proven shape r9-r12)

__device__ __forceinline__ float frcp(float x){ return __builtin_amdgcn_rcpf(x); }
__device__ __forceinline__ float frsq(float x){ return __builtin_amdgcn_rsqf(x); }
__device__ __forceinline__ float fsqrt_(float x){ return __builtin_amdgcn_sqrtf(x); }

__device__ __forceinline__ float sysloadf(const float* p) {
    return __hip_atomic_load(p, __ATOMIC_RELAXED, __HIP_MEMORY_SCOPE_SYSTEM);
}
__device__ __forceinline__ void sysstoref(float* p, float v) {
    __hip_atomic_store(p, v, __ATOMIC_RELAXED, __HIP_MEMORY_SCOPE_SYSTEM);
}
__device__ __forceinline__ unsigned sysloadu(const unsigned* p) {
    return __hip_atomic_load(p, __ATOMIC_RELAXED, __HIP_MEMORY_SCOPE_SYSTEM);
}
__device__ __forceinline__ void sysstoreu(unsigned* p, unsigned v) {
    __hip_atomic_store(p, v, __ATOMIC_RELAXED, __HIP_MEMORY_SCOPE_SYSTEM);
}

__device__ __forceinline__ float wave_max(float v) {
    #pragma unroll
    for (int k = 32; k >= 1; k >>= 1)
        v = fmaxf(v, __shfl_xor(v, k));
    return v;
}

#define CTRL_TOTAL (NSLOT * ANBLK)

// Sign-SET sentinel = "unpublished" (deterministic regardless of ws poison).
__global__ void bmax_init(unsigned* z) {
    for (int i = threadIdx.x; i < CTRL_TOTAL; i += 256) z[i] = 0xAAAAAAAAu;
}

// One Roe flux from window-index j (cells j | j+1).
__device__ __forceinline__ void roe1(const float rr[6], const float uu[6],
                                     const float pp[6], const float ss[6],
                                     const float gg[6], int j,
                                     float& Frj, float& Fmj, float& Fej) {
    float sL = ss[j], sR = ss[j + 1];
    float uL = uu[j], uR = uu[j + 1];
    float invden = frcp(sL + sR);
    float ur = (sL * uL + sR * uR) * invden;
    float Hr = (gg[j] + gg[j + 1]) * invden;
    float c  = fsqrt_(fmaxf(GM1 * (Hr - 0.5f * ur * ur), 1e-10f));
    float eps = EFIX * c;
    float l1 = ur - c, l3 = ur + c;
    float a1 = fsqrt_(l1 * l1 + eps * eps);
    float a2 = fsqrt_(ur * ur + eps * eps);
    float a3 = fsqrt_(l3 * l3 + eps * eps);
    float drho = rr[j + 1] - rr[j];
    float du   = uR - uL;
    float dp   = pp[j + 1] - pp[j];
    float c2 = c * c;
    float inv2c2 = frcp(c2 + c2);
    float al2 = drho - (dp + dp) * inv2c2;
    float tcd = c * rr[j + 1] * du;
    float al1 = (dp - tcd) * inv2c2;
    float al3 = (dp + tcd) * inv2c2;
    float FrL = rr[j] * uL, FrR = rr[j + 1] * uR;
    float FmL = FrL * uL + pp[j], FmR = FrR * uR + pp[j + 1];
    float FeL = uL * (gg[j] * sL), FeR = uR * (gg[j + 1] * sR);
    float w1 = a1 * al1, w2 = a2 * al2, w3 = a3 * al3;
    Frj = 0.5f * (FrL + FrR - (w1 + w2 + w3));
    Fmj = 0.5f * (FmL + FmR - (w1 * l1 + w2 * ur + w3 * l3));
    Fej = 0.5f * (FeL + FeR - (w1 * (Hr - ur * c) + w2 * (0.5f * ur * ur)
                               + w3 * (Hr + ur * c)));
}

__global__ __launch_bounds__(ABLK, 4) void euler_async(
        const float* __restrict__ rho0, const float* __restrict__ u0,
        const float* __restrict__ p0, const float* __restrict__ tf,
        float* __restrict__ out, unsigned* __restrict__ bmax,
        float* __restrict__ halo) {   // halo: NSLOT rows x ANBLK x 10
    __shared__ float Lr[ABLK], Lu[ABLK], Lp[ABLK], Ls[ABLK], Lg[ABLK]; // cell3
    __shared__ float Rr[ABLK], Ru[ABLK], Rp[ABLK], Rs[ABLK], Rg[ABLK]; // cell0
    __shared__ float fxr[ABLK], fxm[ABLK], fxe[ABLK];                  // flux0
    __shared__ float red[ABLK / 64];
    __shared__ float samax;

    const int tid = threadIdx.x, bid = blockIdx.x;
    const int c0 = bid * ATILE + ACPT * tid;
    const int lane = tid & 63, wid = tid >> 6;

    float cr[4], cu[4], cp[4], cs[4], cg[4];

    // ---- prepass: inputs -> regs (incl s,g); publish halo+bmax row 0 ----
    {
        float4 r4 = *(const float4*)(rho0 + c0);
        float4 u4 = *(const float4*)(u0 + c0);
        float4 p4 = *(const float4*)(p0 + c0);
        cr[0]=r4.x; cr[1]=r4.y; cr[2]=r4.z; cr[3]=r4.w;
        cu[0]=u4.x; cu[1]=u4.y; cu[2]=u4.z; cu[3]=u4.w;
        cp[0]=p4.x; cp[1]=p4.y; cp[2]=p4.z; cp[3]=p4.w;
        float nm = 0.f;
        #pragma unroll
        for (int c = 0; c < 4; ++c) {
            float E = cp[c] * IGM1 + 0.5f * cr[c] * cu[c] * cu[c];
            float q = frsq(cr[c]);
            cs[c] = cr[c] * q;
            cg[c] = (E + cp[c]) * q;
            nm = fmaxf(nm, fabsf(cu[c]) + fsqrt_(GAM * cp[c] * (q * q)));
        }
        Lr[tid]=cr[3]; Lu[tid]=cu[3]; Lp[tid]=cp[3]; Ls[tid]=cs[3]; Lg[tid]=cg[3];
        Rr[tid]=cr[0]; Ru[tid]=cu[0]; Rp[tid]=cp[0]; Rs[tid]=cs[0]; Rg[tid]=cg[0];
        if (tid == 0) {
            float* h = halo + (size_t)bid * 10;
            sysstoref(h, cr[0]); sysstoref(h+1, cu[0]); sysstoref(h+2, cp[0]);
            sysstoref(h+3, cs[0]); sysstoref(h+4, cg[0]);
        }
        if (tid == ABLK - 1) {
            float* h = halo + (size_t)bid * 10 + 5;
            sysstoref(h, cr[3]); sysstoref(h+1, cu[3]); sysstoref(h+2, cp[3]);
            sysstoref(h+3, cs[3]); sysstoref(h+4, cg[3]);
        }
        nm = wave_max(nm);
        if (lane == 0) red[wid] = nm;
        __syncthreads();      // drains every wave's halo stores + red[]
        if (tid == 0) {
            float bm = red[0];
            #pragma unroll
            for (int w = 1; w < ABLK / 64; ++w) bm = fmaxf(bm, red[w]);
            sysstoreu(&bmax[bid], __float_as_uint(bm));   // sign clear
        }
    }
    float t = 0.f;
    const float tfin = *tf;

    for (int k = 0; k < NSTEPS; ++k) {
        const unsigned* brow = bmax + (size_t)k * ANBLK;

        // window: idx 0..5 = cells c0-1 .. c0+4 (state k), with s,g carried
        float rr[6], uu[6], pp[6], ss[6], gg[6];
        #pragma unroll
        for (int c = 0; c < 4; ++c) {
            rr[c+1]=cr[c]; uu[c+1]=cu[c]; pp[c+1]=cp[c];
            ss[c+1]=cs[c]; gg[c+1]=cg[c];
        }
        if (tid == 0) {
            if (bid > 0) {   // neighbor's bmax publish implies its halo row k
                while (sysloadu(&brow[bid - 1]) & 0x80000000u)
                    __builtin_amdgcn_s_sleep(1);
                const float* h = halo + ((size_t)k * ANBLK + (bid - 1)) * 10 + 5;
                rr[0]=sysloadf(h);   uu[0]=sysloadf(h+1); pp[0]=sysloadf(h+2);
                ss[0]=sysloadf(h+3); gg[0]=sysloadf(h+4);
            } else {
                rr[0]=cr[0]; uu[0]=cu[0]; pp[0]=cp[0]; ss[0]=cs[0]; gg[0]=cg[0];
            }
        } else {
            rr[0]=Lr[tid-1]; uu[0]=Lu[tid-1]; pp[0]=Lp[tid-1];
            ss[0]=Ls[tid-1]; gg[0]=Lg[tid-1];
        }
        if (tid == ABLK - 1) {
            if (bid < ANBLK - 1) {
                while (sysloadu(&brow[bid + 1]) & 0x80000000u)
                    __builtin_amdgcn_s_sleep(1);
                const float* h = halo + ((size_t)k * ANBLK + (bid + 1)) * 10;
                rr[5]=sysloadf(h);   uu[5]=sysloadf(h+1); pp[5]=sysloadf(h+2);
                ss[5]=sysloadf(h+3); gg[5]=sysloadf(h+4);
            } else {
                rr[5]=cr[3]; uu[5]=cu[3]; pp[5]=cp[3]; ss[5]=cs[3]; gg[5]=cg[3];
            }
        } else {
            rr[5]=Rr[tid+1]; uu[5]=Ru[tid+1]; pp[5]=Rp[tid+1];
            ss[5]=Rs[tid+1]; gg[5]=Rg[tid+1];
        }

        // fluxes 0..3; flux 4 from tid+1 via LDS (edge thread computes own)
        float Fr[5], Fm[5], Fe[5];
        #pragma unroll
        for (int j = 0; j < 4; ++j)
            roe1(rr, uu, pp, ss, gg, j, Fr[j], Fm[j], Fe[j]);
        fxr[tid] = Fr[0]; fxm[tid] = Fm[0]; fxe[tid] = Fe[0];
        if (tid == ABLK - 1)
            roe1(rr, uu, pp, ss, gg, 4, Fr[4], Fm[4], Fe[4]);

        // wave 0: poll all 256 bmax entries sign-clear (coalesced), then max
        if (wid == 0) {
            unsigned v0, v1, v2, v3;
            for (;;) {
                v0 = sysloadu(&brow[lane]);
                v1 = sysloadu(&brow[64 + lane]);
                v2 = sysloadu(&brow[128 + lane]);
                v3 = sysloadu(&brow[192 + lane]);
                if (__all(((v0 | v1 | v2 | v3) & 0x80000000u) == 0u)) break;
                __builtin_amdgcn_s_sleep(1);
            }
            float m = fmaxf(fmaxf(__uint_as_float(v0), __uint_as_float(v1)),
                            fmaxf(__uint_as_float(v2), __uint_as_float(v3)));
            m = wave_max(m);
            if (lane == 0) samax = m;
        }
        __syncthreads();   // #1: samax + flux LDS ready; state LDS reads done

        if (tid < ABLK - 1) {
            Fr[4] = fxr[tid + 1]; Fm[4] = fxm[tid + 1]; Fe[4] = fxe[tid + 1];
        }
        float amax = samax;
        float dt = fminf((CFLC * DXC) * frcp(amax), fmaxf(tfin - t, 0.f));
        t += dt;
        float dtdx = dt * IDXC;

        float nm = 0.f;
        #pragma unroll
        for (int i = 1; i <= 4; ++i) {
            float E  = gg[i] * ss[i] - pp[i];           // (E+p) - p
            float r2 = rr[i]         - dtdx * (Fr[i] - Fr[i-1]);
            float m2 = rr[i] * uu[i] - dtdx * (Fm[i] - Fm[i-1]);
            float E2 = E             - dtdx * (Fe[i] - Fe[i-1]);
            float q2 = frsq(r2);
            float ir = q2 * q2;
            float u2 = m2 * ir;
            float p2 = GM1 * (E2 - 0.5f * r2 * u2 * u2);
            cr[i-1]=r2; cu[i-1]=u2; cp[i-1]=p2;
            cs[i-1]=r2 * q2;                 // == next step's r2*frsq(r2)
            cg[i-1]=(E2 + p2) * q2;          // conservative E2, as in ref
            nm = fmaxf(nm, fabsf(u2) + fsqrt_(GAM * p2 * ir));
        }

        if (k < NSTEPS - 1) {
            Lr[tid]=cr[3]; Lu[tid]=cu[3]; Lp[tid]=cp[3]; Ls[tid]=cs[3]; Lg[tid]=cg[3];
            Rr[tid]=cr[0]; Ru[tid]=cu[0]; Rp[tid]=cp[0]; Rs[tid]=cs[0]; Rg[tid]=cg[0];
            if (tid == 0) {
                float* h = halo + ((size_t)(k + 1) * ANBLK + bid) * 10;
                sysstoref(h, cr[0]); sysstoref(h+1, cu[0]); sysstoref(h+2, cp[0]);
                sysstoref(h+3, cs[0]); sysstoref(h+4, cg[0]);
            }
            if (tid == ABLK - 1) {
                float* h = halo + ((size_t)(k + 1) * ANBLK + bid) * 10 + 5;
                sysstoref(h, cr[3]); sysstoref(h+1, cu[3]); sysstoref(h+2, cp[3]);
                sysstoref(h+3, cs[3]); sysstoref(h+4, cg[3]);
            }
            nm = wave_max(nm);
            if (lane == 0) red[wid] = nm;
            __syncthreads();   // #2: drains halo stores; LDS ready for k+1
            if (tid == 0) {
                float bm = red[0];
                #pragma unroll
                for (int w = 1; w < ABLK / 64; ++w) bm = fmaxf(bm, red[w]);
                sysstoreu(&bmax[(size_t)(k + 1) * ANBLK + bid],
                          __float_as_uint(bm));          // sign clear
            }
        } else {
            *(float4*)(out + c0)         = make_float4(cr[0], cr[1], cr[2], cr[3]);
            *(float4*)(out + NXC + c0)   = make_float4(cu[0], cu[1], cu[2], cu[3]);
            *(float4*)(out + 2*NXC + c0) = make_float4(cp[0], cp[1], cp[2], cp[3]);
        }
    }
}

extern "C" void kernel_launch(void* const* d_in, const int* in_sizes, int n_in,
                              void* d_out, int out_size, void* d_ws, size_t ws_size,
                              hipStream_t stream) {
    const float* rho0 = (const float*)d_in[0];
    const float* u0   = (const float*)d_in[1];
    const float* p0   = (const float*)d_in[2];
    const float* tf   = (const float*)d_in[3];
    // d_in[4] = n_steps (fixed at 32)

    float* out      = (float*)d_out;
    unsigned* bmax  = (unsigned*)d_ws;                   // 33*256 uints
    float* halo     = (float*)(bmax + CTRL_TOTAL);       // 33*256*10 floats

    bmax_init<<<1, 256, 0, stream>>>(bmax);

    // Unconditional cooperative launch (no host queries: they fail during
    // stream capture and silently swap the timed graph -- round-11 lesson).
    void* args[] = {(void*)&rho0, (void*)&u0, (void*)&p0, (void*)&tf,
                    (void*)&out, (void*)&bmax, (void*)&halo};
    hipLaunchCooperativeKernel((void*)euler_async, dim3(ANBLK), dim3(ABLK),
                               args, 0, stream);
}

// Round 14
// 226.947 us; speedup vs baseline: 1.1451x; 1.1451x over previous
//
#include <hip/hip_runtime.h>

// 1D Euler, Roe flux + Harten entropy fix, 32 steps. Round 14:
// round-12 skeleton EXACTLY (37 KB LDS, 3-float exchanges, one-hop dt)
// + REGISTER-ONLY carry of s=sqrt(rho), g=(E+p)/sqrt(rho), and E.
//
// Round-13 lesson: widening the LDS/halo exchange to move s,g regressed
// 157->180 us (8 extra LDS ops/thread/step + 53.8 KB LDS + 43 MB HBM) even
// though VALU issue dropped. Register-local work is nearly free; moving
// data is not. So r14 keeps r12's exchange byte-for-byte and only:
//  - carries cs=r2*q2 (bit-identical to recompute: q2=frsq(r2) already in
//    the update), cg=(E2+p2)*q2, cE=E2 (conservative, like the reference)
//    in VGPRs across steps;
//  - window s,g: own cells 1..4 from carried regs; 2 neighbor cells
//    recomputed from the same 3-float r,u,p exchange as r12 (2 frsq vs
//    r12's 6 frsq per thread per step);
//  - update uses carried cE (drops E = g*s - p re-derivation);
//  - keeps r13's harmless micro-fixes: coalesced poll loads, frcp for dt.
// Block-boundary fluxes differ ~1 ulp between sides (carried vs recomputed
// g) -- 1e-7-class vs threshold 0.034. Interior fluxes computed once.

#define NXC   1048576
#define GAM   1.4f
#define GM1   0.4f
#define IGM1  2.5f
#define CFLC  0.5f
#define DXC   1e-3f
#define IDXC  1000.0f
#define EFIX  0.1f
#define NSTEPS 32
#define NSLOT  (NSTEPS + 1)

#define ABLK  1024
#define ACPT  4
#define ATILE (ABLK*ACPT)      // 4096
#define ANBLK (NXC/ATILE)      // 256 blocks = 1/CU (proven shape r9-r13)

__device__ __forceinline__ float frcp(float x){ return __builtin_amdgcn_rcpf(x); }
__device__ __forceinline__ float frsq(float x){ return __builtin_amdgcn_rsqf(x); }
__device__ __forceinline__ float fsqrt_(float x){ return __builtin_amdgcn_sqrtf(x); }

__device__ __forceinline__ float sysloadf(const float* p) {
    return __hip_atomic_load(p, __ATOMIC_RELAXED, __HIP_MEMORY_SCOPE_SYSTEM);
}
__device__ __forceinline__ void sysstoref(float* p, float v) {
    __hip_atomic_store(p, v, __ATOMIC_RELAXED, __HIP_MEMORY_SCOPE_SYSTEM);
}
__device__ __forceinline__ unsigned sysloadu(const unsigned* p) {
    return __hip_atomic_load(p, __ATOMIC_RELAXED, __HIP_MEMORY_SCOPE_SYSTEM);
}
__device__ __forceinline__ void sysstoreu(unsigned* p, unsigned v) {
    __hip_atomic_store(p, v, __ATOMIC_RELAXED, __HIP_MEMORY_SCOPE_SYSTEM);
}

__device__ __forceinline__ float wave_max(float v) {
    #pragma unroll
    for (int k = 32; k >= 1; k >>= 1)
        v = fmaxf(v, __shfl_xor(v, k));
    return v;
}

#define CTRL_TOTAL (NSLOT * ANBLK)

// Sign-SET sentinel = "unpublished" (deterministic regardless of ws poison).
__global__ void bmax_init(unsigned* z) {
    for (int i = threadIdx.x; i < CTRL_TOTAL; i += 256) z[i] = 0xAAAAAAAAu;
}

// One Roe flux from window-index j (cells j | j+1).
__device__ __forceinline__ void roe1(const float rr[6], const float uu[6],
                                     const float pp[6], const float ss[6],
                                     const float gg[6], int j,
                                     float& Frj, float& Fmj, float& Fej) {
    float sL = ss[j], sR = ss[j + 1];
    float uL = uu[j], uR = uu[j + 1];
    float invden = frcp(sL + sR);
    float ur = (sL * uL + sR * uR) * invden;
    float Hr = (gg[j] + gg[j + 1]) * invden;
    float c  = fsqrt_(fmaxf(GM1 * (Hr - 0.5f * ur * ur), 1e-10f));
    float eps = EFIX * c;
    float l1 = ur - c, l3 = ur + c;
    float a1 = fsqrt_(l1 * l1 + eps * eps);
    float a2 = fsqrt_(ur * ur + eps * eps);
    float a3 = fsqrt_(l3 * l3 + eps * eps);
    float drho = rr[j + 1] - rr[j];
    float du   = uR - uL;
    float dp   = pp[j + 1] - pp[j];
    float c2 = c * c;
    float inv2c2 = frcp(c2 + c2);
    float al2 = drho - (dp + dp) * inv2c2;
    float tcd = c * rr[j + 1] * du;
    float al1 = (dp - tcd) * inv2c2;
    float al3 = (dp + tcd) * inv2c2;
    float FrL = rr[j] * uL, FrR = rr[j + 1] * uR;
    float FmL = FrL * uL + pp[j], FmR = FrR * uR + pp[j + 1];
    float FeL = uL * (gg[j] * sL), FeR = uR * (gg[j + 1] * sR);
    float w1 = a1 * al1, w2 = a2 * al2, w3 = a3 * al3;
    Frj = 0.5f * (FrL + FrR - (w1 + w2 + w3));
    Fmj = 0.5f * (FmL + FmR - (w1 * l1 + w2 * ur + w3 * l3));
    Fej = 0.5f * (FeL + FeR - (w1 * (Hr - ur * c) + w2 * (0.5f * ur * ur)
                               + w3 * (Hr + ur * c)));
}

__global__ __launch_bounds__(ABLK, 4) void euler_async(
        const float* __restrict__ rho0, const float* __restrict__ u0,
        const float* __restrict__ p0, const float* __restrict__ tf,
        float* __restrict__ out, unsigned* __restrict__ bmax,
        float* __restrict__ halo) {   // halo: NSLOT rows x ANBLK x 6
    __shared__ float Lr[ABLK], Lu[ABLK], Lp[ABLK];   // each thread's cell3
    __shared__ float Rr[ABLK], Ru[ABLK], Rp[ABLK];   // each thread's cell0
    __shared__ float fxr[ABLK], fxm[ABLK], fxe[ABLK]; // each thread's flux0
    __shared__ float red[ABLK / 64];
    __shared__ float samax;

    const int tid = threadIdx.x, bid = blockIdx.x;
    const int c0 = bid * ATILE + ACPT * tid;
    const int lane = tid & 63, wid = tid >> 6;

    float cr[4], cu[4], cp[4], cE[4], cs[4], cg[4];

    // ---- prepass: inputs -> regs (incl E,s,g); publish halo+bmax row 0 --
    {
        float4 r4 = *(const float4*)(rho0 + c0);
        float4 u4 = *(const float4*)(u0 + c0);
        float4 p4 = *(const float4*)(p0 + c0);
        cr[0]=r4.x; cr[1]=r4.y; cr[2]=r4.z; cr[3]=r4.w;
        cu[0]=u4.x; cu[1]=u4.y; cu[2]=u4.z; cu[3]=u4.w;
        cp[0]=p4.x; cp[1]=p4.y; cp[2]=p4.z; cp[3]=p4.w;
        float nm = 0.f;
        #pragma unroll
        for (int c = 0; c < 4; ++c) {
            float E = cp[c] * IGM1 + 0.5f * cr[c] * cu[c] * cu[c];
            float q = frsq(cr[c]);
            cE[c] = E;
            cs[c] = cr[c] * q;
            cg[c] = (E + cp[c]) * q;
            nm = fmaxf(nm, fabsf(cu[c]) + fsqrt_(GAM * cp[c] * (q * q)));
        }
        Lr[tid]=cr[3]; Lu[tid]=cu[3]; Lp[tid]=cp[3];
        Rr[tid]=cr[0]; Ru[tid]=cu[0]; Rp[tid]=cp[0];
        if (tid == 0) {
            float* h = halo + (size_t)bid * 6;
            sysstoref(h, cr[0]); sysstoref(h+1, cu[0]); sysstoref(h+2, cp[0]);
        }
        if (tid == ABLK - 1) {
            float* h = halo + (size_t)bid * 6 + 3;
            sysstoref(h, cr[3]); sysstoref(h+1, cu[3]); sysstoref(h+2, cp[3]);
        }
        nm = wave_max(nm);
        if (lane == 0) red[wid] = nm;
        __syncthreads();      // drains every wave's halo stores + red[]
        if (tid == 0) {
            float bm = red[0];
            #pragma unroll
            for (int w = 1; w < ABLK / 64; ++w) bm = fmaxf(bm, red[w]);
            sysstoreu(&bmax[bid], __float_as_uint(bm));   // sign clear
        }
    }
    float t = 0.f;
    const float tfin = *tf;

    for (int k = 0; k < NSTEPS; ++k) {
        const unsigned* brow = bmax + (size_t)k * ANBLK;

        // window: idx 0..5 = cells c0-1 .. c0+4 (state k)
        float rr[6], uu[6], pp[6], ss[6], gg[6];
        #pragma unroll
        for (int c = 0; c < 4; ++c) {
            rr[c+1]=cr[c]; uu[c+1]=cu[c]; pp[c+1]=cp[c];
            ss[c+1]=cs[c]; gg[c+1]=cg[c];
        }
        if (tid == 0) {
            if (bid > 0) {   // neighbor's bmax publish implies its halo row k
                while (sysloadu(&brow[bid - 1]) & 0x80000000u)
                    __builtin_amdgcn_s_sleep(1);
                const float* h = halo + ((size_t)k * ANBLK + (bid - 1)) * 6 + 3;
                rr[0]=sysloadf(h); uu[0]=sysloadf(h+1); pp[0]=sysloadf(h+2);
            } else { rr[0]=cr[0]; uu[0]=cu[0]; pp[0]=cp[0]; }
        } else { rr[0]=Lr[tid-1]; uu[0]=Lu[tid-1]; pp[0]=Lp[tid-1]; }
        if (tid == ABLK - 1) {
            if (bid < ANBLK - 1) {
                while (sysloadu(&brow[bid + 1]) & 0x80000000u)
                    __builtin_amdgcn_s_sleep(1);
                const float* h = halo + ((size_t)k * ANBLK + (bid + 1)) * 6;
                rr[5]=sysloadf(h); uu[5]=sysloadf(h+1); pp[5]=sysloadf(h+2);
            } else { rr[5]=cr[3]; uu[5]=cu[3]; pp[5]=cp[3]; }
        } else { rr[5]=Rr[tid+1]; uu[5]=Ru[tid+1]; pp[5]=Rp[tid+1]; }

        // s,g for the 2 neighbor cells only (own 4 carried in regs)
        {
            float E0 = pp[0] * IGM1 + 0.5f * rr[0] * uu[0] * uu[0];
            float q0 = frsq(rr[0]);
            ss[0] = rr[0] * q0;  gg[0] = (E0 + pp[0]) * q0;
            float E5 = pp[5] * IGM1 + 0.5f * rr[5] * uu[5] * uu[5];
            float q5 = frsq(rr[5]);
            ss[5] = rr[5] * q5;  gg[5] = (E5 + pp[5]) * q5;
        }

        // fluxes 0..3; flux 4 from tid+1 via LDS (edge thread computes own)
        float Fr[5], Fm[5], Fe[5];
        #pragma unroll
        for (int j = 0; j < 4; ++j)
            roe1(rr, uu, pp, ss, gg, j, Fr[j], Fm[j], Fe[j]);
        fxr[tid] = Fr[0]; fxm[tid] = Fm[0]; fxe[tid] = Fe[0];
        if (tid == ABLK - 1)
            roe1(rr, uu, pp, ss, gg, 4, Fr[4], Fm[4], Fe[4]);

        // wave 0: poll all 256 bmax entries sign-clear (coalesced), then max
        if (wid == 0) {
            unsigned v0, v1, v2, v3;
            for (;;) {
                v0 = sysloadu(&brow[lane]);
                v1 = sysloadu(&brow[64 + lane]);
                v2 = sysloadu(&brow[128 + lane]);
                v3 = sysloadu(&brow[192 + lane]);
                if (__all(((v0 | v1 | v2 | v3) & 0x80000000u) == 0u)) break;
                __builtin_amdgcn_s_sleep(1);
            }
            float m = fmaxf(fmaxf(__uint_as_float(v0), __uint_as_float(v1)),
                            fmaxf(__uint_as_float(v2), __uint_as_float(v3)));
            m = wave_max(m);
            if (lane == 0) samax = m;
        }
        __syncthreads();   // #1: samax + flux LDS ready; state LDS reads done

        if (tid < ABLK - 1) {
            Fr[4] = fxr[tid + 1]; Fm[4] = fxm[tid + 1]; Fe[4] = fxe[tid + 1];
        }
        float amax = samax;
        float dt = fminf((CFLC * DXC) * frcp(amax), fmaxf(tfin - t, 0.f));
        t += dt;
        float dtdx = dt * IDXC;

        float nm = 0.f;
        #pragma unroll
        for (int i = 1; i <= 4; ++i) {
            float r2 = rr[i]         - dtdx * (Fr[i] - Fr[i-1]);
            float m2 = rr[i] * uu[i] - dtdx * (Fm[i] - Fm[i-1]);
            float E2 = cE[i-1]       - dtdx * (Fe[i] - Fe[i-1]);
            float q2 = frsq(r2);
            float ir = q2 * q2;
            float u2 = m2 * ir;
            float p2 = GM1 * (E2 - 0.5f * r2 * u2 * u2);
            cr[i-1]=r2; cu[i-1]=u2; cp[i-1]=p2; cE[i-1]=E2;
            cs[i-1]=r2 * q2;                 // bit-identical to recompute
            cg[i-1]=(E2 + p2) * q2;          // conservative E2, as in ref
            nm = fmaxf(nm, fabsf(u2) + fsqrt_(GAM * p2 * ir));
        }

        if (k < NSTEPS - 1) {
            Lr[tid]=cr[3]; Lu[tid]=cu[3]; Lp[tid]=cp[3];
            Rr[tid]=cr[0]; Ru[tid]=cu[0]; Rp[tid]=cp[0];
            if (tid == 0) {
                float* h = halo + ((size_t)(k + 1) * ANBLK + bid) * 6;
                sysstoref(h, cr[0]); sysstoref(h+1, cu[0]); sysstoref(h+2, cp[0]);
            }
            if (tid == ABLK - 1) {
                float* h = halo + ((size_t)(k + 1) * ANBLK + bid) * 6 + 3;
                sysstoref(h, cr[3]); sysstoref(h+1, cu[3]); sysstoref(h+2, cp[3]);
            }
            nm = wave_max(nm);
            if (lane == 0) red[wid] = nm;
            __syncthreads();   // #2: drains halo stores; LDS ready for k+1
            if (tid == 0) {
                float bm = red[0];
                #pragma unroll
                for (int w = 1; w < ABLK / 64; ++w) bm = fmaxf(bm, red[w]);
                sysstoreu(&bmax[(size_t)(k + 1) * ANBLK + bid],
                          __float_as_uint(bm));          // sign clear
            }
        } else {
            *(float4*)(out + c0)         = make_float4(cr[0], cr[1], cr[2], cr[3]);
            *(float4*)(out + NXC + c0)   = make_float4(cu[0], cu[1], cu[2], cu[3]);
            *(float4*)(out + 2*NXC + c0) = make_float4(cp[0], cp[1], cp[2], cp[3]);
        }
    }
}

extern "C" void kernel_launch(void* const* d_in, const int* in_sizes, int n_in,
                              void* d_out, int out_size, void* d_ws, size_t ws_size,
                              hipStream_t stream) {
    const float* rho0 = (const float*)d_in[0];
    const float* u0   = (const float*)d_in[1];
    const float* p0   = (const float*)d_in[2];
    const float* tf   = (const float*)d_in[3];
    // d_in[4] = n_steps (fixed at 32)

    float* out      = (float*)d_out;
    unsigned* bmax  = (unsigned*)d_ws;                   // 33*256 uints
    float* halo     = (float*)(bmax + CTRL_TOTAL);       // 33*256*6 floats

    bmax_init<<<1, 256, 0, stream>>>(bmax);

    // Unconditional cooperative launch (no host queries: they fail during
    // stream capture and silently swap the timed graph -- round-11 lesson).
    void* args[] = {(void*)&rho0, (void*)&u0, (void*)&p0, (void*)&tf,
                    (void*)&out, (void*)&bmax, (void*)&halo};
    hipLaunchCooperativeKernel((void*)euler_async, dim3(ANBLK), dim3(ABLK),
                               args, 0, stream);
}